// Round 4
// baseline (846.498 us; speedup 1.0000x reference)
//
#include <hip/hip_runtime.h>
#include <hip/hip_bf16.h>

typedef __hip_bfloat16 bf16;
typedef __attribute__((ext_vector_type(8))) __bf16 bf16x8;
typedef __attribute__((ext_vector_type(4))) float f32x4;

#define MFMA16(a, b, c) __builtin_amdgcn_mfma_f32_16x16x32_bf16((a), (b), (c), 0, 0, 0)

#define BT 4096      // B*T rows
#define CE 2048      // embed dim
#define NQKV 3072    // q(2048) + k(512) + v(512)
#define TSEQ 2048
#define HD 128

#define NEG_BIG (-3.0e30f)   // finite "-inf": exp underflows to 0, no inf/NaN

// ---------------------------------------------------------------------------
// Input-dtype detector. If inputs are fp32 and we misread them as bf16, the
// even uint16 words are low mantissa halves (uniform bits -> arbitrary
// exponents, incl. NaN encodings). For true-bf16 N(0,1) data, even words are
// bf16 values with exponent in ~[117,130]. Count plausible exponents over 256
// samples: bf16 -> ~256, fp32 -> ~14.  flag=1 means "inputs are fp32".
__global__ void detect_dtype(const unsigned short* __restrict__ x, int* __restrict__ flag)
{
    __shared__ int cnt;
    if (threadIdx.x == 0) cnt = 0;
    __syncthreads();
    unsigned short w = x[2 * threadIdx.x];
    int e = (w >> 7) & 0xFF;
    atomicAdd(&cnt, (e >= 117 && e <= 130) ? 1 : 0);
    __syncthreads();
    if (threadIdx.x == 0) *flag = (cnt < 128) ? 1 : 0;
}

// Stage 8 elements (16B of bf16) into LDS from either a bf16 or an fp32 source.
__device__ __forceinline__ void stage8(short* dst, const void* src, size_t eoff, bool f32)
{
    if (f32) {
        const float* s = (const float*)src + eoff;
        float4 f0 = *(const float4*)s;
        float4 f1 = *(const float4*)(s + 4);
        bf16x8 v;
        v[0] = (__bf16)f0.x; v[1] = (__bf16)f0.y; v[2] = (__bf16)f0.z; v[3] = (__bf16)f0.w;
        v[4] = (__bf16)f1.x; v[5] = (__bf16)f1.y; v[6] = (__bf16)f1.z; v[7] = (__bf16)f1.w;
        *(bf16x8*)dst = v;
    } else {
        *(uint4*)dst = *(const uint4*)((const bf16*)src + eoff);
    }
}

__device__ __forceinline__ float ldf(const void* p, int i, bool f32)
{
    return f32 ? ((const float*)p)[i] : __bfloat162float(((const bf16*)p)[i]);
}

// ---------------------------------------------------------------------------
// C[M,N] = A[M,K] @ W[N,K]^T, fp32 accum. A row stride = lda (elements).
// W rows [0,s1)->W0, [s1,s2)->W1 (rebased), [s2,N)->W2 (rebased).
// aGate/wGate/oGate: 1 = this pointer follows the detected input dtype
// (fp32 if *flagp). 128x128 tile, 4 waves (2x2) of 64x64, BK=32.
__global__ __launch_bounds__(256)
void gemm_bt(const void* __restrict__ A, const void* __restrict__ W0,
             const void* __restrict__ W1, const void* __restrict__ W2,
             void* __restrict__ C, int M, int N, int K, int lda,
             int s1, int s2, int aGate, int wGate, int oGate,
             const int* __restrict__ flagp)
{
    __shared__ short As[128][48];   // stride 48 elems = 96 B, 16B-aligned rows
    __shared__ short Bs[128][48];

    const int f  = *flagp;
    const bool aF = aGate && f, wF = wGate && f, oF = oGate && f;

    const int tid   = threadIdx.x;
    const int lane  = tid & 63;
    const int wid   = tid >> 6;
    const int row16 = lane & 15;
    const int quad  = lane >> 4;
    const int wr    = wid >> 1;
    const int wc    = wid & 1;
    const int m0    = blockIdx.y * 128;
    const int n0    = blockIdx.x * 128;

    f32x4 acc[4][4];
#pragma unroll
    for (int i = 0; i < 4; i++)
#pragma unroll
        for (int j = 0; j < 4; j++)
            acc[i][j] = (f32x4){0.f, 0.f, 0.f, 0.f};

    for (int k0 = 0; k0 < K; k0 += 32) {
#pragma unroll
        for (int i = 0; i < 2; i++) {
            int c   = i * 256 + tid;
            int row = c >> 2;
            int col = (c & 3) << 3;
            stage8(&As[row][col], A, (size_t)(m0 + row) * lda + k0 + col, aF);
            int g = n0 + row;
            const void* wp; int r;
            if (g < s1)      { wp = W0; r = g; }
            else if (g < s2) { wp = W1; r = g - s1; }
            else             { wp = W2; r = g - s2; }
            stage8(&Bs[row][col], wp, (size_t)r * K + k0 + col, wF);
        }
        __syncthreads();

        bf16x8 af[4], bfv[4];
#pragma unroll
        for (int mi = 0; mi < 4; mi++)
            af[mi] = *(const bf16x8*)&As[wr * 64 + mi * 16 + row16][quad * 8];
#pragma unroll
        for (int ni = 0; ni < 4; ni++)
            bfv[ni] = *(const bf16x8*)&Bs[wc * 64 + ni * 16 + row16][quad * 8];
#pragma unroll
        for (int mi = 0; mi < 4; mi++)
#pragma unroll
            for (int ni = 0; ni < 4; ni++)
                acc[mi][ni] = MFMA16(af[mi], bfv[ni], acc[mi][ni]);
        __syncthreads();
    }

    // epilogue: C/D layout col=lane&15, row=quad*4+reg  [m89-verified]
#pragma unroll
    for (int mi = 0; mi < 4; mi++) {
        int rowb = m0 + wr * 64 + mi * 16 + quad * 4;
#pragma unroll
        for (int ni = 0; ni < 4; ni++) {
            int col = n0 + wc * 64 + ni * 16 + row16;
#pragma unroll
            for (int r = 0; r < 4; r++) {
                size_t idx = (size_t)(rowb + r) * N + col;
                float  v   = acc[mi][ni][r];
                if (oF) ((float*)C)[idx] = v;
                else    ((bf16*)C)[idx]  = __float2bfloat16(v);
            }
        }
    }
}

// ---------------------------------------------------------------------------
// RoPE + RMSNorm on q and k heads, in place inside qkv (always bf16 ws).
// cos/sin come from d_in -> dtype-gated. One wave per (b,t,head-slot);
// lane owns dims (l, l+64) = the rotate-half pairing.
__global__ __launch_bounds__(256)
void rope_rms(bf16* __restrict__ qkv, const void* __restrict__ cosp,
              const void* __restrict__ sinp, const int* __restrict__ flagp)
{
    const bool f = *flagp != 0;
    const int wg   = blockIdx.x * 4 + (threadIdx.x >> 6);
    const int lane = threadIdx.x & 63;
    const int s    = wg % 20;
    const int m    = wg / 20;         // b*T + t
    const int t    = m & (TSEQ - 1);

    const int col = (s < 16) ? s * HD : CE + (s - 16) * HD;
    bf16* p = qkv + (size_t)m * NQKV + col;

    float xlo = __bfloat162float(p[lane]);
    float xhi = __bfloat162float(p[lane + 64]);
    float cl  = ldf(cosp, t * HD + lane, f);
    float sl  = ldf(sinp, t * HD + lane, f);
    float ch  = ldf(cosp, t * HD + 64 + lane, f);
    float sh  = ldf(sinp, t * HD + 64 + lane, f);

    float rlo = xlo * cl - xhi * sl;
    float rhi = xhi * ch + xlo * sh;

    float ss = rlo * rlo + rhi * rhi;
#pragma unroll
    for (int off = 32; off > 0; off >>= 1)
        ss += __shfl_xor(ss, off, 64);
    float inv = rsqrtf(ss * (1.0f / 128.0f) + 1.1920929e-07f);

    p[lane]      = __float2bfloat16(rlo * inv);
    p[lane + 64] = __float2bfloat16(rhi * inv);
}

// ---------------------------------------------------------------------------
// vt[b, hk, d, t] = qkv[(b*T+t)*3072 + 2560 + hk*128 + d]
__global__ __launch_bounds__(256)
void vtrans(const bf16* __restrict__ qkv, bf16* __restrict__ vt)
{
    int idx = blockIdx.x * 256 + threadIdx.x;
    int t  = idx & (TSEQ - 1);
    int d  = (idx >> 11) & 127;
    int bh = idx >> 18;
    vt[idx] = qkv[((size_t)((bh >> 2) * TSEQ + t)) * NQKV + 2560 + (bh & 3) * HD + d];
}

// ---------------------------------------------------------------------------
// Flash attention. grid=(T/64, B*H), block=256 (4 waves, 16 q-rows each).
// Q/K read from qkv (stride NQKV). Output O is written back IN PLACE into
// qkv's Q columns (col h*128, rows q0..q0+15): only this same wave ever
// reads those cells (as aq, loaded before the loop), so no race. The proj
// GEMM then reads qkv cols 0..2047 with lda=3072. Saves a 16.8MB buffer.
__global__ __launch_bounds__(256)
void attn(bf16* __restrict__ qkv, const bf16* __restrict__ vt)
{
    __shared__ bf16 Pl[4][16][32];   // per-wave P tile (C->A layout round trip)

    const int lane  = threadIdx.x & 63;
    const int wid   = threadIdx.x >> 6;
    const int row16 = lane & 15;
    const int quad  = lane >> 4;
    const int b  = blockIdx.y >> 4;
    const int h  = blockIdx.y & 15;
    const int hk = h >> 2;
    const int q0 = blockIdx.x * 64 + wid * 16;

    const bf16* Q  = qkv + ((size_t)(b * TSEQ + q0)) * NQKV + h * HD;
    const bf16* Kp = qkv + ((size_t)(b * TSEQ)) * NQKV + CE + hk * HD;
    const bf16* Vp = vt + ((size_t)(b * 4 + hk) * HD) * TSEQ;

    bf16x8 aq[4];
#pragma unroll
    for (int ds = 0; ds < 4; ds++)
        aq[ds] = *(const bf16x8*)(Q + (size_t)row16 * NQKV + ds * 32 + quad * 8);

    f32x4 o[8];
#pragma unroll
    for (int dt = 0; dt < 8; dt++) o[dt] = (f32x4){0.f, 0.f, 0.f, 0.f};
    float mr[4], lr[4];
#pragma unroll
    for (int r = 0; r < 4; r++) { mr[r] = NEG_BIG; lr[r] = 0.f; }

    const float sc = 0.08838834764831845f;   // 1/sqrt(128)
    const int kend = q0 + 15;

    for (int k0 = 0; k0 <= kend; k0 += 32) {
        f32x4 s0 = (f32x4){0.f, 0.f, 0.f, 0.f};
        f32x4 s1 = (f32x4){0.f, 0.f, 0.f, 0.f};
#pragma unroll
        for (int ds = 0; ds < 4; ds++) {
            bf16x8 kf0 = *(const bf16x8*)(Kp + (size_t)(k0 + row16) * NQKV + ds * 32 + quad * 8);
            bf16x8 kf1 = *(const bf16x8*)(Kp + (size_t)(k0 + 16 + row16) * NQKV + ds * 32 + quad * 8);
            s0 = MFMA16(aq[ds], kf0, s0);
            s1 = MFMA16(aq[ds], kf1, s1);
        }

#pragma unroll
        for (int r = 0; r < 4; r++) {
            int qrow = q0 + quad * 4 + r;
            float v0 = (k0 + row16      <= qrow) ? s0[r] * sc : NEG_BIG;
            float v1 = (k0 + 16 + row16 <= qrow) ? s1[r] * sc : NEG_BIG;
            float mx = fmaxf(v0, v1);
#pragma unroll
            for (int off = 1; off < 16; off <<= 1)
                mx = fmaxf(mx, __shfl_xor(mx, off, 64));
            float mnew  = fmaxf(mr[r], mx);
            float p0    = __expf(v0 - mnew);
            float p1    = __expf(v1 - mnew);
            float alpha = __expf(mr[r] - mnew);
            float sum = p0 + p1;
#pragma unroll
            for (int off = 1; off < 16; off <<= 1)
                sum += __shfl_xor(sum, off, 64);
            lr[r] = lr[r] * alpha + sum;
            mr[r] = mnew;
#pragma unroll
            for (int dt = 0; dt < 8; dt++) o[dt][r] *= alpha;
            Pl[wid][quad * 4 + r][row16]      = __float2bfloat16(p0);
            Pl[wid][quad * 4 + r][16 + row16] = __float2bfloat16(p1);
        }

        // C-layout -> A-layout via wave-private LDS. Compiler fences pin
        // instruction order; explicit s_waitcnt lgkmcnt(0) (imm 0xC07F:
        // vmcnt=63, expcnt=7, lgkmcnt=0) guarantees the ds_writes retired
        // before the ds_read issues.
        __asm__ volatile("" ::: "memory");
        __builtin_amdgcn_s_waitcnt(0xC07F);
        bf16x8 pf = *(const bf16x8*)&Pl[wid][row16][quad * 8];
        __asm__ volatile("" ::: "memory");

#pragma unroll
        for (int dt = 0; dt < 8; dt++) {
            bf16x8 vf = *(const bf16x8*)(Vp + (size_t)(dt * 16 + row16) * TSEQ + k0 + quad * 8);
            o[dt] = MFMA16(pf, vf, o[dt]);
        }
    }

    // write O back into qkv's Q slot (cols h*128..h*128+127)
#pragma unroll
    for (int r = 0; r < 4; r++) {
        float rl = 1.0f / lr[r];
        int t = q0 + quad * 4 + r;
        bf16* dst = qkv + ((size_t)(b * TSEQ + t)) * NQKV + h * HD;
#pragma unroll
        for (int dt = 0; dt < 8; dt++)
            dst[dt * 16 + row16] = __float2bfloat16(o[dt][r] * rl);
    }
}

// ---------------------------------------------------------------------------
extern "C" void kernel_launch(void* const* d_in, const int* in_sizes, int n_in,
                              void* d_out, int out_size, void* d_ws, size_t ws_size,
                              hipStream_t stream)
{
    // ws layout (bf16 elems): qkv [4096,3072] 25.2MB | vt [2,4,128,2048] 4.2MB
    // | dtype flag (int). Total ~28MB.
    bf16* qkv  = (bf16*)d_ws;
    bf16* vt   = qkv + (size_t)BT * NQKV;
    int* flagp = (int*)(vt + (size_t)2 * 4 * HD * TSEQ);

    // 0) detect input dtype (bf16 vs fp32) -> device flag
    detect_dtype<<<1, 256, 0, stream>>>((const unsigned short*)d_in[0], flagp);

    // 1) fused QKV projection (A=x gated, W=wq/wk/wv gated, C=qkv bf16)
    gemm_bt<<<dim3(NQKV / 128, BT / 128), 256, 0, stream>>>(
        d_in[0], d_in[3], d_in[4], d_in[5], qkv,
        BT, NQKV, CE, CE, 2048, 2560, 1, 1, 0, flagp);

    // 2) V transpose to [B,KV,D,T]
    vtrans<<<(2 * 4 * HD * TSEQ) / 256, 256, 0, stream>>>(qkv, vt);

    // 3) RoPE + RMSNorm for q,k in place (cos/sin gated)
    rope_rms<<<(BT * 20) / 4, 256, 0, stream>>>(qkv, d_in[1], d_in[2], flagp);

    // 4) flash attention; O overwrites qkv's Q columns
    attn<<<dim3(TSEQ / 64, 2 * 16), 256, 0, stream>>>(qkv, vt);

    // 5) output projection: A = qkv cols 0..2047 (lda=3072), C = d_out (gated dtype)
    gemm_bt<<<dim3(CE / 128, BT / 128), 256, 0, stream>>>(
        qkv, d_in[6], d_in[6], d_in[6], d_out,
        BT, CE, CE, NQKV, CE, CE, 0, 1, 1, flagp);
}

// Round 5
// 587.105 us; speedup vs baseline: 1.4418x; 1.4418x over previous
//
#include <hip/hip_runtime.h>
#include <hip/hip_bf16.h>

typedef __hip_bfloat16 bf16;
typedef __attribute__((ext_vector_type(8))) __bf16 bf16x8;
typedef __attribute__((ext_vector_type(4))) float f32x4;

#define MFMA16(a, b, c) __builtin_amdgcn_mfma_f32_16x16x32_bf16((a), (b), (c), 0, 0, 0)

#define BT 4096      // B*T rows
#define CE 2048      // embed dim
#define NQKV 3072    // q(2048) + k(512) + v(512)
#define TSEQ 2048
#define HD 128

#define NEG_BIG (-3.0e30f)   // finite "-inf": exp underflows to 0, no inf/NaN

// ---------------------------------------------------------------------------
// Input-dtype detector (confirmed R4: inputs are fp32; keep the gate for
// robustness). flag=1 means "inputs are fp32".
__global__ void detect_dtype(const unsigned short* __restrict__ x, int* __restrict__ flag)
{
    __shared__ int cnt;
    if (threadIdx.x == 0) cnt = 0;
    __syncthreads();
    unsigned short w = x[2 * threadIdx.x];
    int e = (w >> 7) & 0xFF;
    atomicAdd(&cnt, (e >= 117 && e <= 130) ? 1 : 0);
    __syncthreads();
    if (threadIdx.x == 0) *flag = (cnt < 128) ? 1 : 0;
}

// Stage 8 elements (16B of bf16) into LDS from either a bf16 or an fp32 source.
__device__ __forceinline__ void stage8(short* dst, const void* src, size_t eoff, bool f32)
{
    if (f32) {
        const float* s = (const float*)src + eoff;
        float4 f0 = *(const float4*)s;
        float4 f1 = *(const float4*)(s + 4);
        bf16x8 v;
        v[0] = (__bf16)f0.x; v[1] = (__bf16)f0.y; v[2] = (__bf16)f0.z; v[3] = (__bf16)f0.w;
        v[4] = (__bf16)f1.x; v[5] = (__bf16)f1.y; v[6] = (__bf16)f1.z; v[7] = (__bf16)f1.w;
        *(bf16x8*)dst = v;
    } else {
        *(uint4*)dst = *(const uint4*)((const bf16*)src + eoff);
    }
}

__device__ __forceinline__ float ldf(const void* p, int i, bool f32)
{
    return f32 ? ((const float*)p)[i] : __bfloat162float(((const bf16*)p)[i]);
}

// ---------------------------------------------------------------------------
// C[M,N] = A[M,K] @ W[N,K]^T, fp32 accum. (unchanged from R4)
__global__ __launch_bounds__(256)
void gemm_bt(const void* __restrict__ A, const void* __restrict__ W0,
             const void* __restrict__ W1, const void* __restrict__ W2,
             void* __restrict__ C, int M, int N, int K, int lda,
             int s1, int s2, int aGate, int wGate, int oGate,
             const int* __restrict__ flagp)
{
    __shared__ short As[128][48];
    __shared__ short Bs[128][48];

    const int f  = *flagp;
    const bool aF = aGate && f, wF = wGate && f, oF = oGate && f;

    const int tid   = threadIdx.x;
    const int lane  = tid & 63;
    const int wid   = tid >> 6;
    const int row16 = lane & 15;
    const int quad  = lane >> 4;
    const int wr    = wid >> 1;
    const int wc    = wid & 1;
    const int m0    = blockIdx.y * 128;
    const int n0    = blockIdx.x * 128;

    f32x4 acc[4][4];
#pragma unroll
    for (int i = 0; i < 4; i++)
#pragma unroll
        for (int j = 0; j < 4; j++)
            acc[i][j] = (f32x4){0.f, 0.f, 0.f, 0.f};

    for (int k0 = 0; k0 < K; k0 += 32) {
#pragma unroll
        for (int i = 0; i < 2; i++) {
            int c   = i * 256 + tid;
            int row = c >> 2;
            int col = (c & 3) << 3;
            stage8(&As[row][col], A, (size_t)(m0 + row) * lda + k0 + col, aF);
            int g = n0 + row;
            const void* wp; int r;
            if (g < s1)      { wp = W0; r = g; }
            else if (g < s2) { wp = W1; r = g - s1; }
            else             { wp = W2; r = g - s2; }
            stage8(&Bs[row][col], wp, (size_t)r * K + k0 + col, wF);
        }
        __syncthreads();

        bf16x8 af[4], bfv[4];
#pragma unroll
        for (int mi = 0; mi < 4; mi++)
            af[mi] = *(const bf16x8*)&As[wr * 64 + mi * 16 + row16][quad * 8];
#pragma unroll
        for (int ni = 0; ni < 4; ni++)
            bfv[ni] = *(const bf16x8*)&Bs[wc * 64 + ni * 16 + row16][quad * 8];
#pragma unroll
        for (int mi = 0; mi < 4; mi++)
#pragma unroll
            for (int ni = 0; ni < 4; ni++)
                acc[mi][ni] = MFMA16(af[mi], bfv[ni], acc[mi][ni]);
        __syncthreads();
    }

#pragma unroll
    for (int mi = 0; mi < 4; mi++) {
        int rowb = m0 + wr * 64 + mi * 16 + quad * 4;
#pragma unroll
        for (int ni = 0; ni < 4; ni++) {
            int col = n0 + wc * 64 + ni * 16 + row16;
#pragma unroll
            for (int r = 0; r < 4; r++) {
                size_t idx = (size_t)(rowb + r) * N + col;
                float  v   = acc[mi][ni][r];
                if (oF) ((float*)C)[idx] = v;
                else    ((bf16*)C)[idx]  = __float2bfloat16(v);
            }
        }
    }
}

// ---------------------------------------------------------------------------
// RoPE + RMSNorm in place in qkv (unchanged from R4).
__global__ __launch_bounds__(256)
void rope_rms(bf16* __restrict__ qkv, const void* __restrict__ cosp,
              const void* __restrict__ sinp, const int* __restrict__ flagp)
{
    const bool f = *flagp != 0;
    const int wg   = blockIdx.x * 4 + (threadIdx.x >> 6);
    const int lane = threadIdx.x & 63;
    const int s    = wg % 20;
    const int m    = wg / 20;
    const int t    = m & (TSEQ - 1);

    const int col = (s < 16) ? s * HD : CE + (s - 16) * HD;
    bf16* p = qkv + (size_t)m * NQKV + col;

    float xlo = __bfloat162float(p[lane]);
    float xhi = __bfloat162float(p[lane + 64]);
    float cl  = ldf(cosp, t * HD + lane, f);
    float sl  = ldf(sinp, t * HD + lane, f);
    float ch  = ldf(cosp, t * HD + 64 + lane, f);
    float sh  = ldf(sinp, t * HD + 64 + lane, f);

    float rlo = xlo * cl - xhi * sl;
    float rhi = xhi * ch + xlo * sh;

    float ss = rlo * rlo + rhi * rhi;
#pragma unroll
    for (int off = 32; off > 0; off >>= 1)
        ss += __shfl_xor(ss, off, 64);
    float inv = rsqrtf(ss * (1.0f / 128.0f) + 1.1920929e-07f);

    p[lane]      = __float2bfloat16(rlo * inv);
    p[lane + 64] = __float2bfloat16(rhi * inv);
}

// ---------------------------------------------------------------------------
// vt[b, hk, d, t] = qkv[(b*T+t)*3072 + 2560 + hk*128 + d]  (unchanged)
__global__ __launch_bounds__(256)
void vtrans(const bf16* __restrict__ qkv, bf16* __restrict__ vt)
{
    int idx = blockIdx.x * 256 + threadIdx.x;
    int t  = idx & (TSEQ - 1);
    int d  = (idx >> 11) & 127;
    int bh = idx >> 18;
    vt[idx] = qkv[((size_t)((bh >> 2) * TSEQ + t)) * NQKV + 2560 + (bh & 3) * HD + d];
}

// ---------------------------------------------------------------------------
// Flash attention, RESTRUCTURED (R5): cooperative LDS staging of 64-key
// K-tile + V^T-tile per block, K-step 64. grid=(T/64, B*H), block=256
// (4 waves x 16 q-rows). With 64 q-rows per block and 64-key tiles, every
// wave participates in every tile (the diagonal tile is the last).
// O written in place into qkv's Q columns (race-free: only this wave reads
// those cells, as aq, before the loop).
__global__ __launch_bounds__(256)
void attn(bf16* __restrict__ qkv, const bf16* __restrict__ vt)
{
    __shared__ __bf16 Ks[64][136];    // 64 keys x 128 dims (+8 pad), 16B-aligned rows
    __shared__ __bf16 Vs[128][72];    // 128 dims x 64 keys (+8 pad)
    __shared__ __bf16 Pl[4][16][72];  // per-wave P tile (C->A layout round trip)

    const int tid   = threadIdx.x;
    const int lane  = tid & 63;
    const int wid   = tid >> 6;
    const int row16 = lane & 15;
    const int quad  = lane >> 4;
    const int b  = blockIdx.y >> 4;
    const int h  = blockIdx.y & 15;
    const int hk = h >> 2;
    const int q0b = blockIdx.x * 64;       // block's q-tile start
    const int q0  = q0b + wid * 16;        // wave's q rows

    const bf16* Q  = qkv + ((size_t)(b * TSEQ + q0)) * NQKV + h * HD;
    const bf16* Kp = qkv + ((size_t)(b * TSEQ)) * NQKV + CE + hk * HD;
    const bf16* Vp = vt + ((size_t)(b * 4 + hk) * HD) * TSEQ;

    // Q fragments: A[m=lane&15][k=quad*8+j], 4 chunks over D=128
    bf16x8 aq[4];
#pragma unroll
    for (int ds = 0; ds < 4; ds++)
        aq[ds] = *(const bf16x8*)(Q + (size_t)row16 * NQKV + ds * 32 + quad * 8);

    f32x4 o[8];
#pragma unroll
    for (int dt = 0; dt < 8; dt++) o[dt] = (f32x4){0.f, 0.f, 0.f, 0.f};
    float mr[4], lr[4];
#pragma unroll
    for (int r = 0; r < 4; r++) { mr[r] = NEG_BIG; lr[r] = 0.f; }

    const float sc = 0.08838834764831845f;   // 1/sqrt(128)
    const int ntiles = blockIdx.x + 1;

    for (int t = 0; t < ntiles; t++) {
        const int k0 = t * 64;

        __syncthreads();   // previous iteration's LDS reads done
        // stage K tile: 64 rows x 128 cols; 16 lanes x 16B per row, 4 passes
#pragma unroll
        for (int p4 = 0; p4 < 4; p4++) {
            int row = p4 * 16 + (tid >> 4);
            int col = (tid & 15) * 8;
            *(uint4*)&Ks[row][col] =
                *(const uint4*)(Kp + (size_t)(k0 + row) * NQKV + col);
        }
        // stage V^T tile: 128 rows (d) x 64 cols (t); 8 lanes x 16B per row, 4 passes
#pragma unroll
        for (int p4 = 0; p4 < 4; p4++) {
            int row = p4 * 32 + (tid >> 3);
            int col = (tid & 7) * 8;
            *(uint4*)&Vs[row][col] =
                *(const uint4*)(Vp + (size_t)row * TSEQ + k0 + col);
        }
        __syncthreads();

        // QK^T: 4 key-groups of 16, accumulate s[kg]
        f32x4 s[4];
#pragma unroll
        for (int kg = 0; kg < 4; kg++) s[kg] = (f32x4){0.f, 0.f, 0.f, 0.f};
#pragma unroll
        for (int ds = 0; ds < 4; ds++) {
#pragma unroll
            for (int kg = 0; kg < 4; kg++) {
                bf16x8 kf = *(const bf16x8*)&Ks[kg * 16 + row16][ds * 32 + quad * 8];
                s[kg] = MFMA16(aq[ds], kf, s[kg]);
            }
        }

        // online softmax over 64 keys
#pragma unroll
        for (int r = 0; r < 4; r++) {
            int qrow = q0 + quad * 4 + r;
            float v[4];
#pragma unroll
            for (int kg = 0; kg < 4; kg++)
                v[kg] = (k0 + kg * 16 + row16 <= qrow) ? s[kg][r] * sc : NEG_BIG;
            float mx = fmaxf(fmaxf(v[0], v[1]), fmaxf(v[2], v[3]));
#pragma unroll
            for (int off = 1; off < 16; off <<= 1)
                mx = fmaxf(mx, __shfl_xor(mx, off, 64));
            float mnew  = fmaxf(mr[r], mx);
            float p[4];
            float sum = 0.f;
#pragma unroll
            for (int kg = 0; kg < 4; kg++) { p[kg] = __expf(v[kg] - mnew); sum += p[kg]; }
#pragma unroll
            for (int off = 1; off < 16; off <<= 1)
                sum += __shfl_xor(sum, off, 64);
            float alpha = __expf(mr[r] - mnew);
            lr[r] = lr[r] * alpha + sum;
            mr[r] = mnew;
#pragma unroll
            for (int dt = 0; dt < 8; dt++) o[dt][r] *= alpha;
#pragma unroll
            for (int kg = 0; kg < 4; kg++)
                Pl[wid][quad * 4 + r][kg * 16 + row16] = (__bf16)p[kg];
        }

        // C-layout -> A-layout via wave-private LDS (same-wave DS ops are
        // in-order; fence pins compiler ordering)
        __asm__ volatile("" ::: "memory");
#pragma unroll
        for (int c = 0; c < 2; c++) {
            bf16x8 pf = *(const bf16x8*)&Pl[wid][row16][c * 32 + quad * 8];
#pragma unroll
            for (int dt = 0; dt < 8; dt++) {
                bf16x8 vf = *(const bf16x8*)&Vs[dt * 16 + row16][c * 32 + quad * 8];
                o[dt] = MFMA16(pf, vf, o[dt]);
            }
        }
        __asm__ volatile("" ::: "memory");
    }

    // write O back into qkv's Q slot
#pragma unroll
    for (int r = 0; r < 4; r++) {
        float rl = 1.0f / lr[r];
        int t = q0 + quad * 4 + r;
        bf16* dst = qkv + ((size_t)(b * TSEQ + t)) * NQKV + h * HD;
#pragma unroll
        for (int dt = 0; dt < 8; dt++)
            dst[dt * 16 + row16] = __float2bfloat16(o[dt][r] * rl);
    }
}

// ---------------------------------------------------------------------------
extern "C" void kernel_launch(void* const* d_in, const int* in_sizes, int n_in,
                              void* d_out, int out_size, void* d_ws, size_t ws_size,
                              hipStream_t stream)
{
    // ws layout (bf16 elems): qkv [4096,3072] 25.2MB | vt [2,4,128,2048] 4.2MB
    // | dtype flag (int). Total ~28MB.
    bf16* qkv  = (bf16*)d_ws;
    bf16* vt   = qkv + (size_t)BT * NQKV;
    int* flagp = (int*)(vt + (size_t)2 * 4 * HD * TSEQ);

    // 0) detect input dtype (bf16 vs fp32) -> device flag
    detect_dtype<<<1, 256, 0, stream>>>((const unsigned short*)d_in[0], flagp);

    // 1) fused QKV projection (A=x gated, W=wq/wk/wv gated, C=qkv bf16)
    gemm_bt<<<dim3(NQKV / 128, BT / 128), 256, 0, stream>>>(
        d_in[0], d_in[3], d_in[4], d_in[5], qkv,
        BT, NQKV, CE, CE, 2048, 2560, 1, 1, 0, flagp);

    // 2) V transpose to [B,KV,D,T]
    vtrans<<<(2 * 4 * HD * TSEQ) / 256, 256, 0, stream>>>(qkv, vt);

    // 3) RoPE + RMSNorm for q,k in place (cos/sin gated)
    rope_rms<<<(BT * 20) / 4, 256, 0, stream>>>(qkv, d_in[1], d_in[2], flagp);

    // 4) flash attention (LDS-staged); O overwrites qkv's Q columns
    attn<<<dim3(TSEQ / 64, 2 * 16), 256, 0, stream>>>(qkv, vt);

    // 5) output projection: A = qkv cols 0..2047 (lda=3072), C = d_out (gated dtype)
    gemm_bt<<<dim3(CE / 128, BT / 128), 256, 0, stream>>>(
        qkv, d_in[6], d_in[6], d_in[6], d_out,
        BT, CE, CE, NQKV, CE, CE, 0, 1, 1, flagp);
}

// Round 6
// 515.713 us; speedup vs baseline: 1.6414x; 1.1384x over previous
//
#include <hip/hip_runtime.h>
#include <hip/hip_bf16.h>

typedef __hip_bfloat16 bf16;
typedef __attribute__((ext_vector_type(8))) __bf16 bf16x8;
typedef __attribute__((ext_vector_type(4))) float f32x4;

#define MFMA16(a, b, c) __builtin_amdgcn_mfma_f32_16x16x32_bf16((a), (b), (c), 0, 0, 0)

#define BT 4096      // B*T rows
#define CE 2048      // embed dim
#define NQKV 3072    // q(2048) + k(512) + v(512)
#define TSEQ 2048
#define HD 128

// q pre-scale: 1/sqrt(128) * log2(e), folded into rope_rms's q output.
#define QSCALE (0.08838834764831845f * 1.4426950408889634f)
// fixed softmax max bound: ||q'|| * ||k|| = 128 * QSCALE (Cauchy-Schwarz on
// RMS-normalized vectors). p = 2^(s' - M2) <= ~1, no online max needed.
#define M2 16.3222f

// ---------------------------------------------------------------------------
// async global->LDS 16B copy (one instruction, no VGPR round trip)
__device__ __forceinline__ void gld16(const void* g, void* l)
{
    __builtin_amdgcn_global_load_lds(
        (const __attribute__((address_space(1))) void*)g,
        (__attribute__((address_space(3))) void*)l, 16, 0, 0);
}

// ---------------------------------------------------------------------------
// Input-dtype detector (R4-confirmed: inputs are fp32; gate kept for safety).
__global__ void detect_dtype(const unsigned short* __restrict__ x, int* __restrict__ flag)
{
    __shared__ int cnt;
    if (threadIdx.x == 0) cnt = 0;
    __syncthreads();
    unsigned short w = x[2 * threadIdx.x];
    int e = (w >> 7) & 0xFF;
    atomicAdd(&cnt, (e >= 117 && e <= 130) ? 1 : 0);
    __syncthreads();
    if (threadIdx.x == 0) *flag = (cnt < 128) ? 1 : 0;
}

// Stage 8 elems (16B bf16) into LDS from bf16 or fp32 source (VGPR convert).
__device__ __forceinline__ void stage8(short* dst, const void* src, size_t eoff, bool f32)
{
    if (f32) {
        const float* s = (const float*)src + eoff;
        float4 f0 = *(const float4*)s;
        float4 f1 = *(const float4*)(s + 4);
        bf16x8 v;
        v[0] = (__bf16)f0.x; v[1] = (__bf16)f0.y; v[2] = (__bf16)f0.z; v[3] = (__bf16)f0.w;
        v[4] = (__bf16)f1.x; v[5] = (__bf16)f1.y; v[6] = (__bf16)f1.z; v[7] = (__bf16)f1.w;
        *(bf16x8*)dst = v;
    } else {
        *(uint4*)dst = *(const uint4*)((const bf16*)src + eoff);
    }
}

__device__ __forceinline__ float ldf(const void* p, int i, bool f32)
{
    return f32 ? ((const float*)p)[i] : __bfloat162float(((const bf16*)p)[i]);
}

// ---------------------------------------------------------------------------
// fp32 (or bf16) -> bf16 conversion, 8 elems/thread.
__global__ __launch_bounds__(256)
void conv_bf16(const void* __restrict__ src, bf16* __restrict__ dst,
               const int* __restrict__ flagp)
{
    const bool f = *flagp != 0;
    size_t i8 = (size_t)blockIdx.x * 256 + threadIdx.x;
    stage8((short*)(dst + i8 * 8), src, i8 * 8, f);
}

// ---------------------------------------------------------------------------
// C[M,N] = A[M,K] @ W[N,K]^T, fp32 accum. 128x128 tile, 4 waves 64x64, BK=32.
// W is fused bf16 [N][K]. A: bf16 (async LDS DMA) or fp32 (VGPR convert) per
// aGate&flag. C: bf16 or fp32 per oGate&flag. LDS tiles UNPADDED [128][32]
// so lds addr == wave base + lane*16 (global_load_lds constraint, m97/m104).
__global__ __launch_bounds__(256)
void gemm_bt(const void* __restrict__ A, const bf16* __restrict__ W,
             void* __restrict__ C, int M, int N, int K, int lda,
             int aGate, int oGate, const int* __restrict__ flagp)
{
    __shared__ short As[128][32];
    __shared__ short Bs[128][32];

    const int f = *flagp;
    const bool aF = aGate && f, oF = oGate && f;

    const int tid   = threadIdx.x;
    const int lane  = tid & 63;
    const int wid   = tid >> 6;
    const int row16 = lane & 15;
    const int quad  = lane >> 4;
    const int wr    = wid >> 1;
    const int wc    = wid & 1;
    const int m0    = blockIdx.y * 128;
    const int n0    = blockIdx.x * 128;

    const int rl4 = wid * 16 + (lane >> 2);   // staging row within 64
    const int c8  = (lane & 3) * 8;           // staging col (elements)

    f32x4 acc[4][4];
#pragma unroll
    for (int i = 0; i < 4; i++)
#pragma unroll
        for (int j = 0; j < 4; j++)
            acc[i][j] = (f32x4){0.f, 0.f, 0.f, 0.f};

    for (int k0 = 0; k0 < K; k0 += 32) {
        // W tile: 2 async wave-loads (lds = &Bs[row][c8] == base + lane*16)
#pragma unroll
        for (int i = 0; i < 2; i++) {
            int r = i * 64 + rl4;
            gld16(W + (size_t)(n0 + r) * K + k0 + c8, &Bs[r][c8]);
        }
        if (!aF) {
#pragma unroll
            for (int i = 0; i < 2; i++) {
                int r = i * 64 + rl4;
                gld16((const bf16*)A + (size_t)(m0 + r) * lda + k0 + c8, &As[r][c8]);
            }
        } else {
#pragma unroll
            for (int i = 0; i < 2; i++) {
                int c = i * 256 + tid;
                int row = c >> 2, col = (c & 3) << 3;
                stage8(&As[row][col], A, (size_t)(m0 + row) * lda + k0 + col, true);
            }
        }
        __syncthreads();   // drains vmcnt (lds-DMA) + lgkmcnt (ds_write)

        bf16x8 af[4], bfv[4];
#pragma unroll
        for (int mi = 0; mi < 4; mi++)
            af[mi] = *(const bf16x8*)&As[wr * 64 + mi * 16 + row16][quad * 8];
#pragma unroll
        for (int ni = 0; ni < 4; ni++)
            bfv[ni] = *(const bf16x8*)&Bs[wc * 64 + ni * 16 + row16][quad * 8];
#pragma unroll
        for (int mi = 0; mi < 4; mi++)
#pragma unroll
            for (int ni = 0; ni < 4; ni++)
                acc[mi][ni] = MFMA16(af[mi], bfv[ni], acc[mi][ni]);
        __syncthreads();
    }

    // epilogue: C/D layout col=lane&15, row=quad*4+reg  [m89-verified]
#pragma unroll
    for (int mi = 0; mi < 4; mi++) {
        int rowb = m0 + wr * 64 + mi * 16 + quad * 4;
#pragma unroll
        for (int ni = 0; ni < 4; ni++) {
            int col = n0 + wc * 64 + ni * 16 + row16;
#pragma unroll
            for (int r = 0; r < 4; r++) {
                size_t idx = (size_t)(rowb + r) * N + col;
                float  v   = acc[mi][ni][r];
                if (oF) ((float*)C)[idx] = v;
                else    ((bf16*)C)[idx]  = __float2bfloat16(v);
            }
        }
    }
}

// ---------------------------------------------------------------------------
// RoPE + RMSNorm in place in qkv. Q heads additionally scaled by QSCALE
// (folds attention's 1/sqrt(D) and log2e into the QK^T result).
__global__ __launch_bounds__(256)
void rope_rms(bf16* __restrict__ qkv, const void* __restrict__ cosp,
              const void* __restrict__ sinp, const int* __restrict__ flagp)
{
    const bool f = *flagp != 0;
    const int wg   = blockIdx.x * 4 + (threadIdx.x >> 6);
    const int lane = threadIdx.x & 63;
    const int s    = wg % 20;
    const int m    = wg / 20;
    const int t    = m & (TSEQ - 1);

    const int col = (s < 16) ? s * HD : CE + (s - 16) * HD;
    bf16* p = qkv + (size_t)m * NQKV + col;

    float xlo = __bfloat162float(p[lane]);
    float xhi = __bfloat162float(p[lane + 64]);
    float cl  = ldf(cosp, t * HD + lane, f);
    float sl  = ldf(sinp, t * HD + lane, f);
    float ch  = ldf(cosp, t * HD + 64 + lane, f);
    float sh  = ldf(sinp, t * HD + 64 + lane, f);

    float rlo = xlo * cl - xhi * sl;
    float rhi = xhi * ch + xlo * sh;

    float ss = rlo * rlo + rhi * rhi;
#pragma unroll
    for (int off = 32; off > 0; off >>= 1)
        ss += __shfl_xor(ss, off, 64);
    float inv = rsqrtf(ss * (1.0f / 128.0f) + 1.1920929e-07f);
    if (s < 16) inv *= QSCALE;

    p[lane]      = __float2bfloat16(rlo * inv);
    p[lane + 64] = __float2bfloat16(rhi * inv);
}

// ---------------------------------------------------------------------------
// vt[b, hk, d, t] = qkv[(b*T+t)*3072 + 2560 + hk*128 + d]
__global__ __launch_bounds__(256)
void vtrans(const bf16* __restrict__ qkv, bf16* __restrict__ vt)
{
    int idx = blockIdx.x * 256 + threadIdx.x;
    int t  = idx & (TSEQ - 1);
    int d  = (idx >> 11) & 127;
    int bh = idx >> 18;
    vt[idx] = qkv[((size_t)((bh >> 2) * TSEQ + t)) * NQKV + 2560 + (bh & 3) * HD + d];
}

// ---------------------------------------------------------------------------
// Flash attention with FIXED-MAX softmax (no online max/alpha/rescale):
// q pre-scaled by QSCALE, so P = 2^(s - M2); per-lane partial row sums
// accumulate across tiles, one 16-lane reduction at the end. Masking only on
// the (wave-uniform) diagonal tile. blockIdx.x reversed so heavy q-blocks
// dispatch first (causal load-balance tail fix). O written in place into
// qkv's Q columns.
__global__ __launch_bounds__(256)
void attn(bf16* __restrict__ qkv, const bf16* __restrict__ vt)
{
    __shared__ __bf16 Ks[64][136];
    __shared__ __bf16 Vs[128][72];
    __shared__ __bf16 Pl[4][16][72];

    const int tid   = threadIdx.x;
    const int lane  = tid & 63;
    const int wid   = tid >> 6;
    const int row16 = lane & 15;
    const int quad  = lane >> 4;
    const int b  = blockIdx.y >> 4;
    const int h  = blockIdx.y & 15;
    const int hk = h >> 2;
    const int xi = gridDim.x - 1 - blockIdx.x;   // reversed: heavy blocks first
    const int q0 = xi * 64 + wid * 16;

    const bf16* Q  = qkv + ((size_t)(b * TSEQ + q0)) * NQKV + h * HD;
    const bf16* Kp = qkv + ((size_t)(b * TSEQ)) * NQKV + CE + hk * HD;
    const bf16* Vp = vt + ((size_t)(b * 4 + hk) * HD) * TSEQ;

    bf16x8 aq[4];
#pragma unroll
    for (int ds = 0; ds < 4; ds++)
        aq[ds] = *(const bf16x8*)(Q + (size_t)row16 * NQKV + ds * 32 + quad * 8);

    f32x4 o[8];
#pragma unroll
    for (int dt = 0; dt < 8; dt++) o[dt] = (f32x4){0.f, 0.f, 0.f, 0.f};
    float lsum[4] = {0.f, 0.f, 0.f, 0.f};

    for (int t = 0; t <= xi; t++) {
        const int k0 = t * 64;
        const bool diag = (t == xi);          // block-uniform branch

        __syncthreads();   // prior iteration's Vs/Ks reads complete
#pragma unroll
        for (int p4 = 0; p4 < 4; p4++) {
            int row = p4 * 16 + (tid >> 4);
            int col = (tid & 15) * 8;
            *(uint4*)&Ks[row][col] =
                *(const uint4*)(Kp + (size_t)(k0 + row) * NQKV + col);
        }
#pragma unroll
        for (int p4 = 0; p4 < 4; p4++) {
            int row = p4 * 32 + (tid >> 3);
            int col = (tid & 7) * 8;
            *(uint4*)&Vs[row][col] =
                *(const uint4*)(Vp + (size_t)row * TSEQ + k0 + col);
        }
        __syncthreads();

        // QK^T: 4 key-groups of 16
        f32x4 s[4];
#pragma unroll
        for (int kg = 0; kg < 4; kg++) s[kg] = (f32x4){0.f, 0.f, 0.f, 0.f};
#pragma unroll
        for (int ds = 0; ds < 4; ds++) {
#pragma unroll
            for (int kg = 0; kg < 4; kg++) {
                bf16x8 kf = *(const bf16x8*)&Ks[kg * 16 + row16][ds * 32 + quad * 8];
                s[kg] = MFMA16(aq[ds], kf, s[kg]);
            }
        }

        // fixed-max softmax numerators; accumulate per-lane partial sums
#pragma unroll
        for (int r = 0; r < 4; r++) {
            float p[4];
            if (diag) {
                int qrow = q0 + quad * 4 + r;
#pragma unroll
                for (int kg = 0; kg < 4; kg++)
                    p[kg] = (k0 + kg * 16 + row16 <= qrow)
                          ? __builtin_amdgcn_exp2f(s[kg][r] - M2) : 0.f;
            } else {
#pragma unroll
                for (int kg = 0; kg < 4; kg++)
                    p[kg] = __builtin_amdgcn_exp2f(s[kg][r] - M2);
            }
            lsum[r] += (p[0] + p[1]) + (p[2] + p[3]);
#pragma unroll
            for (int kg = 0; kg < 4; kg++)
                Pl[wid][quad * 4 + r][kg * 16 + row16] = (__bf16)p[kg];
        }

        // C-layout -> A-layout via wave-private LDS (fences pin ordering)
        __asm__ volatile("" ::: "memory");
#pragma unroll
        for (int c = 0; c < 2; c++) {
            bf16x8 pf = *(const bf16x8*)&Pl[wid][row16][c * 32 + quad * 8];
#pragma unroll
            for (int dt = 0; dt < 8; dt++) {
                bf16x8 vf = *(const bf16x8*)&Vs[dt * 16 + row16][c * 32 + quad * 8];
                o[dt] = MFMA16(pf, vf, o[dt]);
            }
        }
        __asm__ volatile("" ::: "memory");
    }

    // one final 16-lane reduction of l per row, then write O into qkv Q slot
#pragma unroll
    for (int r = 0; r < 4; r++) {
        float l = lsum[r];
#pragma unroll
        for (int off = 1; off < 16; off <<= 1)
            l += __shfl_xor(l, off, 64);
        float rl = 1.0f / l;
        int t = q0 + quad * 4 + r;
        bf16* dst = qkv + ((size_t)(b * TSEQ + t)) * NQKV + h * HD;
#pragma unroll
        for (int dt = 0; dt < 8; dt++)
            dst[dt * 16 + row16] = __float2bfloat16(o[dt][r] * rl);
    }
}

// ---------------------------------------------------------------------------
extern "C" void kernel_launch(void* const* d_in, const int* in_sizes, int n_in,
                              void* d_out, int out_size, void* d_ws, size_t ws_size,
                              hipStream_t stream)
{
    // ws (bf16 elems): qkv [4096,3072] 25.2MB | vt 4.2MB | wqkvb [3072,2048]
    // 12.6MB (reused for wprojb [2048,2048] 8.4MB after gemm1) | flag. ~42MB.
    bf16* qkv   = (bf16*)d_ws;
    bf16* vt    = qkv + (size_t)BT * NQKV;
    bf16* wqkvb = vt + (size_t)2 * 4 * HD * TSEQ;
    int* flagp  = (int*)(wqkvb + (size_t)NQKV * CE);

    // 0) detect input dtype -> device flag
    detect_dtype<<<1, 256, 0, stream>>>((const unsigned short*)d_in[0], flagp);

    // 1) convert wq/wk/wv to fused bf16 [3072][2048]
    conv_bf16<<<(2048 * 2048 / 8) / 256, 256, 0, stream>>>(d_in[3], wqkvb, flagp);
    conv_bf16<<<(512 * 2048 / 8) / 256, 256, 0, stream>>>(d_in[4], wqkvb + (size_t)2048 * 2048, flagp);
    conv_bf16<<<(512 * 2048 / 8) / 256, 256, 0, stream>>>(d_in[5], wqkvb + (size_t)2560 * 2048, flagp);

    // 2) fused QKV projection (A=x fp32-gated convert path, W async-DMA)
    gemm_bt<<<dim3(NQKV / 128, BT / 128), 256, 0, stream>>>(
        d_in[0], wqkvb, qkv, BT, NQKV, CE, CE, 1, 0, flagp);

    // 3) convert wproj into the same buffer (gemm1 done; stream-ordered)
    conv_bf16<<<(2048 * 2048 / 8) / 256, 256, 0, stream>>>(d_in[6], wqkvb, flagp);

    // 4) V transpose to [B,KV,D,T]
    vtrans<<<(2 * 4 * HD * TSEQ) / 256, 256, 0, stream>>>(qkv, vt);

    // 5) RoPE + RMSNorm in place (q additionally scaled by QSCALE)
    rope_rms<<<(BT * 20) / 4, 256, 0, stream>>>(qkv, d_in[1], d_in[2], flagp);

    // 6) flash attention; O overwrites qkv's Q columns
    attn<<<dim3(TSEQ / 64, 2 * 16), 256, 0, stream>>>(qkv, vt);

    // 7) output projection: A=qkv cols 0..2047 (bf16, lda=3072, async DMA)
    gemm_bt<<<dim3(CE / 128, BT / 128), 256, 0, stream>>>(
        qkv, wqkvb, d_out, BT, CE, CE, NQKV, 0, 1, flagp);
}